// Round 5
// baseline (236.130 us; speedup 1.0000x reference)
//
#include <hip/hip_runtime.h>

typedef __bf16 bf16x8 __attribute__((ext_vector_type(8)));
typedef __bf16 bf16x4 __attribute__((ext_vector_type(4)));
typedef float  f32x4  __attribute__((ext_vector_type(4)));
typedef float  f32x2  __attribute__((ext_vector_type(2)));

#define GLDS16(g, l) __builtin_amdgcn_global_load_lds( \
    (const __attribute__((address_space(1))) void*)(g), \
    (__attribute__((address_space(3))) void*)(l), 16, 0, 0)

// fp8 e4m3 (OCP on gfx950). cb holds 64*y in fp8; 1/64 folded into coefs.
#define FP8_SCALE 64.0f
#define FP8_INV   (1.0f / 64.0f)

__device__ __forceinline__ unsigned char fp8_of_f32(float v) {
  return (unsigned char)(__builtin_amdgcn_cvt_pk_fp8_f32(v, v, 0, false) & 0xff);
}
__device__ __forceinline__ void dec4(unsigned int u, float* o) {
  f32x2 lo = __builtin_amdgcn_cvt_pk_f32_fp8(u, false);
  f32x2 hi = __builtin_amdgcn_cvt_pk_f32_fp8(u, true);
  o[0] = lo[0]; o[1] = lo[1]; o[2] = hi[0]; o[3] = hi[1];
}

// ---------------- graph prep ----------------

__global__ void count_kernel(const int* __restrict__ dst, int* __restrict__ cnt, int E) {
  int idx = blockIdx.x * blockDim.x + threadIdx.x;
  int stride = gridDim.x * blockDim.x;
  for (int e = idx; e < E; e += stride) atomicAdd(&cnt[dst[e]], 1);
}

// scan + dinv fused (single workgroup)
__global__ __launch_bounds__(1024) void scan_kernel(const int* __restrict__ cnt,
                                                    int* __restrict__ rowptr,
                                                    float* __restrict__ dinv, int n) {
  __shared__ int part[1024];
  int t = threadIdx.x;
  int CH = (n + 1023) >> 10;
  int base = t * CH;
  int s = 0;
  for (int j = 0; j < CH; j++) {
    int k = base + j;
    if (k < n) { int c = cnt[k]; s += c; dinv[k] = rsqrtf((float)c + 1.0f); }
  }
  part[t] = s;
  __syncthreads();
  for (int off = 1; off < 1024; off <<= 1) {
    int v = (t >= off) ? part[t - off] : 0;
    __syncthreads();
    part[t] += v;
    __syncthreads();
  }
  int run = (t == 0) ? 0 : part[t - 1];
  for (int j = 0; j < CH; j++) { int k = base + j; if (k < n) { rowptr[k] = run; run += cnt[k]; } }
  if (t == 0) rowptr[n] = part[1023];
}

// packed CSR entry: .x = src index, .y = coef bits (coef includes 1/FP8_SCALE)
__global__ void fill_kernel(const int* __restrict__ src, const int* __restrict__ dst,
                            const int* __restrict__ rowptr, int* __restrict__ cur,
                            const float* __restrict__ dinv,
                            int2* __restrict__ csr_pack, int E) {
  int idx = blockIdx.x * blockDim.x + threadIdx.x;
  int stride = gridDim.x * blockDim.x;
  for (int e = idx; e < E; e += stride) {
    int s = src[e], d = dst[e];
    int slot = rowptr[d] + atomicAdd(&cur[d], 1);
    int2 p; p.x = s; p.y = __float_as_int(dinv[s] * dinv[d] * FP8_INV);
    csr_pack[slot] = p;
  }
}

// ---------------- merged conversion: x -> bf16, weights -> transposed bf16 ----------------
// ids [0, 2621440): x float4 chunks; [2621440, 3276800): weight elements.

__global__ void convert_kernel(const float* __restrict__ x,
                               const float* __restrict__ W1, const float* __restrict__ W2,
                               const float* __restrict__ Wmu, const float* __restrict__ Wlv,
                               __bf16* __restrict__ xb,
                               __bf16* __restrict__ w1t, __bf16* __restrict__ w2t,
                               __bf16* __restrict__ wct) {
  int id = blockIdx.x * blockDim.x + threadIdx.x;
  if (id < 2621440) {
    float4 v = ((const float4*)x)[id];
    bf16x4 b;
    b[0] = (__bf16)v.x; b[1] = (__bf16)v.y; b[2] = (__bf16)v.z; b[3] = (__bf16)v.w;
    ((bf16x4*)xb)[id] = b;
  } else {
    int t = id - 2621440;
    if (t < 262144) {
      int nn = t >> 9, kk = t & 511;
      w1t[t] = (__bf16)W1[kk * 512 + nn];
    } else if (t < 524288) {
      int u = t - 262144;
      int nn = u >> 9, kk = u & 511;
      w2t[u] = (__bf16)W2[kk * 512 + nn];
    } else {
      int u = t - 524288;
      int nn = u >> 9, kk = u & 511;     // nn 0..255
      float v = (nn < 128) ? Wmu[kk * 128 + nn] : Wlv[kk * 128 + (nn - 128)];
      wct[u] = (__bf16)v;
    }
  }
}

// ---------------- GEMM: C[M,N] = A[M,K] @ Bt[N,K]^T  (bf16 in, fp8 out) ----------------
// 128x128 tile, BK=32, double-buffered LDS (32 KB total -> 4 blocks/CU), counted
// vmcnt(4). XOR granule swizzle g^((row>>1)&3) applied both-sides (pre-swizzled
// global source + swizzled ds_read; LDS linear for global_load_lds). Bijective
// XCD chunking on a 1D grid.

__global__ __launch_bounds__(256, 4) void gemm_bt(const __bf16* __restrict__ A,
                                                  const __bf16* __restrict__ Bt,
                                                  unsigned char* __restrict__ C,
                                                  int M, int N, int K, int ntiles_n) {
  __shared__ __align__(16) __bf16 sA[2][128 * 32];
  __shared__ __align__(16) __bf16 sB[2][128 * 32];
  const int nb = gridDim.x;
  const int orig = blockIdx.x;
  const int q = nb >> 3, r = nb & 7;
  const int xcd = orig & 7, sub = orig >> 3;
  const int pos = (xcd < r) ? (xcd * (q + 1) + sub) : (r * (q + 1) + (xcd - r) * q + sub);
  const int m0 = (pos / ntiles_n) * 128, n0 = (pos % ntiles_n) * 128;

  const int tid = threadIdx.x;
  const int wave = tid >> 6, lane = tid & 63;
  const int wr = wave >> 1, wc = wave & 1;
  f32x4 acc[4][4] = {};
  const int srow = lane >> 2;                          // 0..15 within 16-row chunk
  const int sg   = (lane & 3) ^ ((srow >> 1) & 3);     // pre-swizzled source granule
  const int nt = K >> 5;

  auto STAGE = [&](int b, int k0) {
    #pragma unroll
    for (int c = 0; c < 2; ++c) {
      int chunk = wave * 2 + c;                        // 0..7, 16 rows each
      int row = chunk * 16 + srow;
      int ga = m0 + row; if (ga >= M) ga = M - 1;
      GLDS16(A  + (long)ga * K         + k0 + sg * 8, sA[b] + chunk * 512);
      GLDS16(Bt + (long)(n0 + row) * K + k0 + sg * 8, sB[b] + chunk * 512);
    }
  };

  STAGE(0, 0);
  for (int t = 0; t < nt; ++t) {
    const int cur = t & 1;
    if (t + 1 < nt) {
      STAGE(cur ^ 1, (t + 1) << 5);
      asm volatile("s_waitcnt vmcnt(4)" ::: "memory");   // cur's 4 loads done
    } else {
      asm volatile("s_waitcnt vmcnt(0)" ::: "memory");
    }
    __builtin_amdgcn_s_barrier();
    __builtin_amdgcn_sched_barrier(0);

    const int fr = lane & 15, gbase = lane >> 4;         // 0..3
    const int gs = gbase ^ ((fr >> 1) & 3);
    bf16x8 af[4], bfr[4];
    #pragma unroll
    for (int mi = 0; mi < 4; mi++)
      af[mi] = *(const bf16x8*)(sA[cur] + (wr * 64 + mi * 16 + fr) * 32 + gs * 8);
    #pragma unroll
    for (int ni = 0; ni < 4; ni++)
      bfr[ni] = *(const bf16x8*)(sB[cur] + (wc * 64 + ni * 16 + fr) * 32 + gs * 8);
    #pragma unroll
    for (int mi = 0; mi < 4; mi++)
      #pragma unroll
      for (int ni = 0; ni < 4; ni++)
        acc[mi][ni] = __builtin_amdgcn_mfma_f32_16x16x32_bf16(af[mi], bfr[ni], acc[mi][ni], 0, 0, 0);
    asm volatile("s_waitcnt lgkmcnt(0)" ::: "memory");
    __builtin_amdgcn_sched_barrier(0);
    __builtin_amdgcn_s_barrier();
  }

  const int crow0 = (lane >> 4) * 4, ccol = lane & 15;
  #pragma unroll
  for (int mi = 0; mi < 4; mi++)
    #pragma unroll
    for (int ni = 0; ni < 4; ni++)
      #pragma unroll
      for (int r2 = 0; r2 < 4; r2++) {
        int row = m0 + wr * 64 + mi * 16 + crow0 + r2;
        if (row < M)
          C[(long)row * N + n0 + wc * 64 + ni * 16 + ccol] =
              fp8_of_f32(acc[mi][ni][r2] * FP8_SCALE);
      }
}

// ---------------- propagation: out = agg + self*h + b, fused epilogues ----------------
// Gathers fp8 rows, f32 accumulate. One wave per node, 8-deep batched gather.
// MODE 0: relu + L2-normalize -> bf16 ; MODE 1: relu -> bf16 ; MODE 2: mu/lv/z -> f32

template<int EPL> struct LSel;
template<> struct LSel<8> { typedef uint2 T; };
template<> struct LSel<4> { typedef unsigned int T; };

template<int EPL, int MODE>
__global__ __launch_bounds__(512) void prop_kernel(
    const unsigned char* __restrict__ Cin, const int* __restrict__ rowptr,
    const int2* __restrict__ csr_pack,
    const float* __restrict__ dinv, const float* __restrict__ bias,
    const float* __restrict__ bmu, const float* __restrict__ blv,
    const float* __restrict__ eps,
    __bf16* __restrict__ hout, float* __restrict__ zout, int n) {
  constexpr int F = EPL * 64;                    // bytes per row
  typedef typename LSel<EPL>::T VecT;
  const int lane = threadIdx.x & 63;
  const int i = blockIdx.x * (blockDim.x >> 6) + (threadIdx.x >> 6);
  if (i >= n) return;
  const unsigned char* __restrict__ Clane = Cin + lane * EPL;

  auto decAll = [&](VecT v, float* o) {
    if constexpr (EPL == 8) { dec4(v.x, o); dec4(v.y, o + 4); }
    else                    { dec4(v, o); }
  };

  float acc[EPL];
  {
    const float di = dinv[i];
    const float sc = di * di * FP8_INV;
    VecT v = *(const VecT*)(Clane + (size_t)i * F);
    float dv[EPL];
    decAll(v, dv);
    #pragma unroll
    for (int j = 0; j < EPL; j++) acc[j] = sc * dv[j];
  }
  int e = rowptr[i];
  const int e1 = rowptr[i + 1];
  for (; e + 8 <= e1; e += 8) {
    int2 p[8];
    #pragma unroll
    for (int q = 0; q < 8; q++) p[q] = csr_pack[e + q];
    VecT v[8];
    #pragma unroll
    for (int q = 0; q < 8; q++) v[q] = *(const VecT*)(Clane + (size_t)p[q].x * F);
    #pragma unroll
    for (int q = 0; q < 8; q++) {
      float c = __int_as_float(p[q].y);
      float dv[EPL];
      decAll(v[q], dv);
      #pragma unroll
      for (int j = 0; j < EPL; j++) acc[j] += c * dv[j];
    }
  }
  for (; e + 4 <= e1; e += 4) {
    int2 p[4];
    #pragma unroll
    for (int q = 0; q < 4; q++) p[q] = csr_pack[e + q];
    VecT v[4];
    #pragma unroll
    for (int q = 0; q < 4; q++) v[q] = *(const VecT*)(Clane + (size_t)p[q].x * F);
    #pragma unroll
    for (int q = 0; q < 4; q++) {
      float c = __int_as_float(p[q].y);
      float dv[EPL];
      decAll(v[q], dv);
      #pragma unroll
      for (int j = 0; j < EPL; j++) acc[j] += c * dv[j];
    }
  }
  for (; e < e1; ++e) {
    int2 p = csr_pack[e];
    float c = __int_as_float(p.y);
    VecT v = *(const VecT*)(Clane + (size_t)p.x * F);
    float dv[EPL];
    decAll(v, dv);
    #pragma unroll
    for (int j = 0; j < EPL; j++) acc[j] += c * dv[j];
  }

  if constexpr (MODE == 0 || MODE == 1) {
    float ss = 0.f;
    #pragma unroll
    for (int j = 0; j < EPL; j++) {
      acc[j] += bias[lane * EPL + j];
      acc[j] = fmaxf(acc[j], 0.f);
      ss += acc[j] * acc[j];
    }
    float scale = 1.f;
    if constexpr (MODE == 0) {
      #pragma unroll
      for (int off = 32; off > 0; off >>= 1) ss += __shfl_xor(ss, off);
      scale = 1.f / fmaxf(sqrtf(ss), 1e-12f);
    }
    bf16x8 o;
    #pragma unroll
    for (int j = 0; j < EPL; j++) o[j] = (__bf16)(acc[j] * scale);
    *(bf16x8*)(hout + (size_t)i * 512 + lane * EPL) = o;
  } else {
    const bool ismu = lane < 32;
    const int cb4 = (ismu ? lane : lane - 32) * 4;
    float v[4];
    #pragma unroll
    for (int j = 0; j < 4; j++) v[j] = acc[j] + (ismu ? bmu[cb4 + j] : blv[cb4 + j]);
    const size_t NZ = (size_t)n * 128;
    float* dstp = ismu ? (zout + NZ + (size_t)i * 128 + cb4)
                       : (zout + 2 * NZ + (size_t)i * 128 + cb4);
    float4 st; st.x = v[0]; st.y = v[1]; st.z = v[2]; st.w = v[3];
    *(float4*)dstp = st;
    float ov[4];
    #pragma unroll
    for (int j = 0; j < 4; j++) ov[j] = __shfl_xor(v[j], 32);
    if (ismu) {
      float4 ev = *(const float4*)(eps + (size_t)i * 128 + cb4);
      float4 zs;
      zs.x = v[0] + ev.x * expf(0.5f * ov[0]);
      zs.y = v[1] + ev.y * expf(0.5f * ov[1]);
      zs.z = v[2] + ev.z * expf(0.5f * ov[2]);
      zs.w = v[3] + ev.w * expf(0.5f * ov[3]);
      *(float4*)(zout + (size_t)i * 128 + cb4) = zs;
    }
  }
}

// ---------------- launch ----------------

extern "C" void kernel_launch(void* const* d_in, const int* in_sizes, int n_in,
                              void* d_out, int out_size, void* d_ws, size_t ws_size,
                              hipStream_t stream) {
  const float* x   = (const float*)d_in[0];
  const int*   ei  = (const int*)d_in[1];
  const float* eps = (const float*)d_in[2];
  const float* W1  = (const float*)d_in[3];
  const float* b1  = (const float*)d_in[4];
  const float* W2  = (const float*)d_in[5];
  const float* b2  = (const float*)d_in[6];
  const float* Wmu = (const float*)d_in[7];
  const float* bmu = (const float*)d_in[8];
  const float* Wlv = (const float*)d_in[9];
  const float* blv = (const float*)d_in[10];
  float* out = (float*)d_out;

  const int N = 20000, E = 320000, D = 512, H = 512, Z = 128;
  const int* src = ei;
  const int* dst = ei + E;

  char* p = (char*)d_ws;
  auto alloc = [&](size_t bytes) { char* r = p; p += (bytes + 255) & ~(size_t)255; return r; };
  int*    cnt      = (int*)alloc((size_t)N * 4);
  int*    cur      = (int*)alloc((size_t)N * 4);
  int*    rowptr   = (int*)alloc((size_t)(N + 1) * 4);
  float*  dinv     = (float*)alloc((size_t)N * 4);
  int2*   csr_pack = (int2*)alloc((size_t)E * 8);
  __bf16* xb  = (__bf16*)alloc((size_t)N * D * 2);
  __bf16* hb  = (__bf16*)alloc((size_t)N * H * 2);
  unsigned char* cb = (unsigned char*)alloc((size_t)N * H);   // fp8 pre-activations
  __bf16* w1t = (__bf16*)alloc((size_t)D * H * 2);
  __bf16* w2t = (__bf16*)alloc((size_t)H * H * 2);
  __bf16* wct = (__bf16*)alloc((size_t)2 * Z * H * 2);

  hipMemsetAsync(cnt, 0, (size_t)N * 4, stream);
  hipMemsetAsync(cur, 0, (size_t)N * 4, stream);

  count_kernel<<<1250, 256, 0, stream>>>(dst, cnt, E);
  scan_kernel<<<1, 1024, 0, stream>>>(cnt, rowptr, dinv, N);
  fill_kernel<<<1250, 256, 0, stream>>>(src, dst, rowptr, cur, dinv, csr_pack, E);
  convert_kernel<<<12800, 256, 0, stream>>>(x, W1, W2, Wmu, Wlv, xb, w1t, w2t, wct);

  // layer 1
  gemm_bt<<<((N + 127) / 128) * (H / 128), 256, 0, stream>>>(xb, w1t, cb, N, H, D, H / 128);
  prop_kernel<8, 0><<<2500, 512, 0, stream>>>(cb, rowptr, csr_pack, dinv,
                                              b1, nullptr, nullptr, nullptr, hb, nullptr, N);
  // layer 2
  gemm_bt<<<((N + 127) / 128) * (H / 128), 256, 0, stream>>>(hb, w2t, cb, N, H, H, H / 128);
  prop_kernel<8, 1><<<2500, 512, 0, stream>>>(cb, rowptr, csr_pack, dinv,
                                              b2, nullptr, nullptr, nullptr, xb, nullptr, N);
  // heads (mu || lv) + reparameterize
  gemm_bt<<<((N + 127) / 128) * ((2 * Z) / 128), 256, 0, stream>>>(xb, wct, cb, N, 2 * Z, H, (2 * Z) / 128);
  prop_kernel<4, 2><<<2500, 512, 0, stream>>>(cb, rowptr, csr_pack, dinv,
                                              nullptr, bmu, blv, eps, nullptr, out, N);
}

// Round 6
// 202.003 us; speedup vs baseline: 1.1689x; 1.1689x over previous
//
#include <hip/hip_runtime.h>

typedef __bf16 bf16x8 __attribute__((ext_vector_type(8)));
typedef __bf16 bf16x4 __attribute__((ext_vector_type(4)));
typedef float  f32x4  __attribute__((ext_vector_type(4)));
typedef float  f32x2  __attribute__((ext_vector_type(2)));

#define GLDS16(g, l) __builtin_amdgcn_global_load_lds( \
    (const __attribute__((address_space(1))) void*)(g), \
    (__attribute__((address_space(3))) void*)(l), 16, 0, 0)

// fp8 e4m3 (OCP on gfx950). cb holds 64*y in fp8; 1/64 folded into coefs.
#define FP8_SCALE 64.0f
#define FP8_INV   (1.0f / 64.0f)

__device__ __forceinline__ unsigned char fp8_of_f32(float v) {
  return (unsigned char)(__builtin_amdgcn_cvt_pk_fp8_f32(v, v, 0, false) & 0xff);
}
__device__ __forceinline__ void dec4(unsigned int u, float* o) {
  f32x2 lo = __builtin_amdgcn_cvt_pk_f32_fp8(u, false);
  f32x2 hi = __builtin_amdgcn_cvt_pk_f32_fp8(u, true);
  o[0] = lo[0]; o[1] = lo[1]; o[2] = hi[0]; o[3] = hi[1];
}

// ---------------- graph prep ----------------

__global__ void count_kernel(const int* __restrict__ dst, int* __restrict__ cnt, int E) {
  int idx = blockIdx.x * blockDim.x + threadIdx.x;
  int stride = gridDim.x * blockDim.x;
  for (int e = idx; e < E; e += stride) atomicAdd(&cnt[dst[e]], 1);
}

// phase 1: per-1024-block exclusive scan (wave shuffle + LDS wave-combine), dinv fused
__global__ __launch_bounds__(1024) void scan1_kernel(const int* __restrict__ cnt,
                                                     int* __restrict__ rowptr,
                                                     float* __restrict__ dinv,
                                                     int* __restrict__ bsum, int n) {
  __shared__ int wsum[16];
  const int t = threadIdx.x, b = blockIdx.x;
  const int gid = b * 1024 + t;
  const int lane = t & 63, w = t >> 6;
  int val = (gid < n) ? cnt[gid] : 0;
  if (gid < n) dinv[gid] = rsqrtf((float)val + 1.0f);
  int incl = val;
  #pragma unroll
  for (int off = 1; off < 64; off <<= 1) {
    int u = __shfl_up(incl, off);
    if (lane >= off) incl += u;
  }
  if (lane == 63) wsum[w] = incl;
  __syncthreads();
  if (w == 0) {
    int v = (lane < 16) ? wsum[lane] : 0;
    int iv = v;
    #pragma unroll
    for (int off = 1; off < 16; off <<= 1) {
      int u = __shfl_up(iv, off);
      if (lane >= off) iv += u;
    }
    if (lane < 16) wsum[lane] = iv - v;      // exclusive wave offset
    if (lane == 15) bsum[b] = iv;            // block total
  }
  __syncthreads();
  if (gid < n) rowptr[gid] = wsum[w] + incl - val;
}

// phase 2: scan the (<=32) block sums serially; set rowptr[n]
__global__ void scan2_kernel(const int* __restrict__ bsum, int* __restrict__ boff,
                             int* __restrict__ rowptr, int nb, int n) {
  if (threadIdx.x == 0 && blockIdx.x == 0) {
    int run = 0;
    for (int b = 0; b < nb; b++) { boff[b] = run; run += bsum[b]; }
    rowptr[n] = run;
  }
}

// phase 3: add block offsets in place
__global__ __launch_bounds__(1024) void scan3_kernel(int* __restrict__ rowptr,
                                                     const int* __restrict__ boff, int n) {
  int gid = blockIdx.x * 1024 + threadIdx.x;
  if (gid < n) rowptr[gid] += boff[blockIdx.x];
}

// packed CSR entry: .x = src index, .y = coef bits (coef includes 1/FP8_SCALE)
__global__ void fill_kernel(const int* __restrict__ src, const int* __restrict__ dst,
                            const int* __restrict__ rowptr, int* __restrict__ cur,
                            const float* __restrict__ dinv,
                            int2* __restrict__ csr_pack, int E) {
  int idx = blockIdx.x * blockDim.x + threadIdx.x;
  int stride = gridDim.x * blockDim.x;
  for (int e = idx; e < E; e += stride) {
    int s = src[e], d = dst[e];
    int slot = rowptr[d] + atomicAdd(&cur[d], 1);
    int2 p; p.x = s; p.y = __float_as_int(dinv[s] * dinv[d] * FP8_INV);
    csr_pack[slot] = p;
  }
}

// ---------------- merged conversion: x -> bf16, weights -> transposed bf16 ----------------

__global__ void convert_kernel(const float* __restrict__ x,
                               const float* __restrict__ W1, const float* __restrict__ W2,
                               const float* __restrict__ Wmu, const float* __restrict__ Wlv,
                               __bf16* __restrict__ xb,
                               __bf16* __restrict__ w1t, __bf16* __restrict__ w2t,
                               __bf16* __restrict__ wct) {
  int id = blockIdx.x * blockDim.x + threadIdx.x;
  if (id < 2621440) {
    float4 v = ((const float4*)x)[id];
    bf16x4 b;
    b[0] = (__bf16)v.x; b[1] = (__bf16)v.y; b[2] = (__bf16)v.z; b[3] = (__bf16)v.w;
    ((bf16x4*)xb)[id] = b;
  } else {
    int t = id - 2621440;
    if (t < 262144) {
      int nn = t >> 9, kk = t & 511;
      w1t[t] = (__bf16)W1[kk * 512 + nn];
    } else if (t < 524288) {
      int u = t - 262144;
      int nn = u >> 9, kk = u & 511;
      w2t[u] = (__bf16)W2[kk * 512 + nn];
    } else {
      int u = t - 524288;
      int nn = u >> 9, kk = u & 511;     // nn 0..255
      float v = (nn < 128) ? Wmu[kk * 128 + nn] : Wlv[kk * 128 + (nn - 128)];
      wct[u] = (__bf16)v;
    }
  }
}

// ---------------- GEMM: C[M,N] = A[M,K] @ Bt[N,K]^T  (bf16 in, fp8 out) ----------------
// 128x128 tile, BK=32, double-buffered LDS (32 KB -> 4 blocks/CU), counted vmcnt(4).
// XOR granule swizzle both-sides. Bijective XCD chunking on a 1D grid.

__global__ __launch_bounds__(256, 4) void gemm_bt(const __bf16* __restrict__ A,
                                                  const __bf16* __restrict__ Bt,
                                                  unsigned char* __restrict__ C,
                                                  int M, int N, int K, int ntiles_n) {
  __shared__ __align__(16) __bf16 sA[2][128 * 32];
  __shared__ __align__(16) __bf16 sB[2][128 * 32];
  const int nb = gridDim.x;
  const int orig = blockIdx.x;
  const int q = nb >> 3, r = nb & 7;
  const int xcd = orig & 7, sub = orig >> 3;
  const int pos = (xcd < r) ? (xcd * (q + 1) + sub) : (r * (q + 1) + (xcd - r) * q + sub);
  const int m0 = (pos / ntiles_n) * 128, n0 = (pos % ntiles_n) * 128;

  const int tid = threadIdx.x;
  const int wave = tid >> 6, lane = tid & 63;
  const int wr = wave >> 1, wc = wave & 1;
  f32x4 acc[4][4] = {};
  const int srow = lane >> 2;
  const int sg   = (lane & 3) ^ ((srow >> 1) & 3);
  const int nt = K >> 5;

  auto STAGE = [&](int b, int k0) {
    #pragma unroll
    for (int c = 0; c < 2; ++c) {
      int chunk = wave * 2 + c;
      int row = chunk * 16 + srow;
      int ga = m0 + row; if (ga >= M) ga = M - 1;
      GLDS16(A  + (long)ga * K         + k0 + sg * 8, sA[b] + chunk * 512);
      GLDS16(Bt + (long)(n0 + row) * K + k0 + sg * 8, sB[b] + chunk * 512);
    }
  };

  STAGE(0, 0);
  for (int t = 0; t < nt; ++t) {
    const int cur = t & 1;
    if (t + 1 < nt) {
      STAGE(cur ^ 1, (t + 1) << 5);
      asm volatile("s_waitcnt vmcnt(4)" ::: "memory");
    } else {
      asm volatile("s_waitcnt vmcnt(0)" ::: "memory");
    }
    __builtin_amdgcn_s_barrier();
    __builtin_amdgcn_sched_barrier(0);

    const int fr = lane & 15, gbase = lane >> 4;
    const int gs = gbase ^ ((fr >> 1) & 3);
    bf16x8 af[4], bfr[4];
    #pragma unroll
    for (int mi = 0; mi < 4; mi++)
      af[mi] = *(const bf16x8*)(sA[cur] + (wr * 64 + mi * 16 + fr) * 32 + gs * 8);
    #pragma unroll
    for (int ni = 0; ni < 4; ni++)
      bfr[ni] = *(const bf16x8*)(sB[cur] + (wc * 64 + ni * 16 + fr) * 32 + gs * 8);
    #pragma unroll
    for (int mi = 0; mi < 4; mi++)
      #pragma unroll
      for (int ni = 0; ni < 4; ni++)
        acc[mi][ni] = __builtin_amdgcn_mfma_f32_16x16x32_bf16(af[mi], bfr[ni], acc[mi][ni], 0, 0, 0);
    asm volatile("s_waitcnt lgkmcnt(0)" ::: "memory");
    __builtin_amdgcn_sched_barrier(0);
    __builtin_amdgcn_s_barrier();
  }

  const int crow0 = (lane >> 4) * 4, ccol = lane & 15;
  #pragma unroll
  for (int mi = 0; mi < 4; mi++)
    #pragma unroll
    for (int ni = 0; ni < 4; ni++)
      #pragma unroll
      for (int r2 = 0; r2 < 4; r2++) {
        int row = m0 + wr * 64 + mi * 16 + crow0 + r2;
        if (row < M)
          C[(long)row * N + n0 + wc * 64 + ni * 16 + ccol] =
              fp8_of_f32(acc[mi][ni][r2] * FP8_SCALE);
      }
}

// ---------------- propagation: out = agg + self*h + b, fused epilogues ----------------

template<int EPL> struct LSel;
template<> struct LSel<8> { typedef uint2 T; };
template<> struct LSel<4> { typedef unsigned int T; };

template<int EPL, int MODE>
__global__ __launch_bounds__(512) void prop_kernel(
    const unsigned char* __restrict__ Cin, const int* __restrict__ rowptr,
    const int2* __restrict__ csr_pack,
    const float* __restrict__ dinv, const float* __restrict__ bias,
    const float* __restrict__ bmu, const float* __restrict__ blv,
    const float* __restrict__ eps,
    __bf16* __restrict__ hout, float* __restrict__ zout, int n) {
  constexpr int F = EPL * 64;                    // bytes per row
  typedef typename LSel<EPL>::T VecT;
  const int lane = threadIdx.x & 63;
  const int i = blockIdx.x * (blockDim.x >> 6) + (threadIdx.x >> 6);
  if (i >= n) return;
  const unsigned char* __restrict__ Clane = Cin + lane * EPL;

  auto decAll = [&](VecT v, float* o) {
    if constexpr (EPL == 8) { dec4(v.x, o); dec4(v.y, o + 4); }
    else                    { dec4(v, o); }
  };

  float acc[EPL];
  {
    const float di = dinv[i];
    const float sc = di * di * FP8_INV;
    VecT v = *(const VecT*)(Clane + (size_t)i * F);
    float dv[EPL];
    decAll(v, dv);
    #pragma unroll
    for (int j = 0; j < EPL; j++) acc[j] = sc * dv[j];
  }
  int e = rowptr[i];
  const int e1 = rowptr[i + 1];
  for (; e + 8 <= e1; e += 8) {
    int2 p[8];
    #pragma unroll
    for (int q = 0; q < 8; q++) p[q] = csr_pack[e + q];
    VecT v[8];
    #pragma unroll
    for (int q = 0; q < 8; q++) v[q] = *(const VecT*)(Clane + (size_t)p[q].x * F);
    #pragma unroll
    for (int q = 0; q < 8; q++) {
      float c = __int_as_float(p[q].y);
      float dv[EPL];
      decAll(v[q], dv);
      #pragma unroll
      for (int j = 0; j < EPL; j++) acc[j] += c * dv[j];
    }
  }
  for (; e + 4 <= e1; e += 4) {
    int2 p[4];
    #pragma unroll
    for (int q = 0; q < 4; q++) p[q] = csr_pack[e + q];
    VecT v[4];
    #pragma unroll
    for (int q = 0; q < 4; q++) v[q] = *(const VecT*)(Clane + (size_t)p[q].x * F);
    #pragma unroll
    for (int q = 0; q < 4; q++) {
      float c = __int_as_float(p[q].y);
      float dv[EPL];
      decAll(v[q], dv);
      #pragma unroll
      for (int j = 0; j < EPL; j++) acc[j] += c * dv[j];
    }
  }
  for (; e < e1; ++e) {
    int2 p = csr_pack[e];
    float c = __int_as_float(p.y);
    VecT v = *(const VecT*)(Clane + (size_t)p.x * F);
    float dv[EPL];
    decAll(v, dv);
    #pragma unroll
    for (int j = 0; j < EPL; j++) acc[j] += c * dv[j];
  }

  if constexpr (MODE == 0 || MODE == 1) {
    float ss = 0.f;
    #pragma unroll
    for (int j = 0; j < EPL; j++) {
      acc[j] += bias[lane * EPL + j];
      acc[j] = fmaxf(acc[j], 0.f);
      ss += acc[j] * acc[j];
    }
    float scale = 1.f;
    if constexpr (MODE == 0) {
      #pragma unroll
      for (int off = 32; off > 0; off >>= 1) ss += __shfl_xor(ss, off);
      scale = 1.f / fmaxf(sqrtf(ss), 1e-12f);
    }
    bf16x8 o;
    #pragma unroll
    for (int j = 0; j < EPL; j++) o[j] = (__bf16)(acc[j] * scale);
    *(bf16x8*)(hout + (size_t)i * 512 + lane * EPL) = o;
  } else {
    const bool ismu = lane < 32;
    const int cb4 = (ismu ? lane : lane - 32) * 4;
    float v[4];
    #pragma unroll
    for (int j = 0; j < 4; j++) v[j] = acc[j] + (ismu ? bmu[cb4 + j] : blv[cb4 + j]);
    const size_t NZ = (size_t)n * 128;
    float* dstp = ismu ? (zout + NZ + (size_t)i * 128 + cb4)
                       : (zout + 2 * NZ + (size_t)i * 128 + cb4);
    float4 st; st.x = v[0]; st.y = v[1]; st.z = v[2]; st.w = v[3];
    *(float4*)dstp = st;
    float ov[4];
    #pragma unroll
    for (int j = 0; j < 4; j++) ov[j] = __shfl_xor(v[j], 32);
    if (ismu) {
      float4 ev = *(const float4*)(eps + (size_t)i * 128 + cb4);
      float4 zs;
      zs.x = v[0] + ev.x * expf(0.5f * ov[0]);
      zs.y = v[1] + ev.y * expf(0.5f * ov[1]);
      zs.z = v[2] + ev.z * expf(0.5f * ov[2]);
      zs.w = v[3] + ev.w * expf(0.5f * ov[3]);
      *(float4*)(zout + (size_t)i * 128 + cb4) = zs;
    }
  }
}

// ---------------- launch ----------------

extern "C" void kernel_launch(void* const* d_in, const int* in_sizes, int n_in,
                              void* d_out, int out_size, void* d_ws, size_t ws_size,
                              hipStream_t stream) {
  const float* x   = (const float*)d_in[0];
  const int*   ei  = (const int*)d_in[1];
  const float* eps = (const float*)d_in[2];
  const float* W1  = (const float*)d_in[3];
  const float* b1  = (const float*)d_in[4];
  const float* W2  = (const float*)d_in[5];
  const float* b2  = (const float*)d_in[6];
  const float* Wmu = (const float*)d_in[7];
  const float* bmu = (const float*)d_in[8];
  const float* Wlv = (const float*)d_in[9];
  const float* blv = (const float*)d_in[10];
  float* out = (float*)d_out;

  const int N = 20000, E = 320000, D = 512, H = 512, Z = 128;
  const int* src = ei;
  const int* dst = ei + E;
  const int NB = (N + 1023) / 1024;     // 20 scan blocks

  char* p = (char*)d_ws;
  auto alloc = [&](size_t bytes) { char* r = p; p += (bytes + 255) & ~(size_t)255; return r; };
  int*    cnt      = (int*)alloc((size_t)N * 4);
  int*    cur      = (int*)alloc((size_t)N * 4);
  int*    rowptr   = (int*)alloc((size_t)(N + 1) * 4);
  float*  dinv     = (float*)alloc((size_t)N * 4);
  int*    bsum     = (int*)alloc((size_t)NB * 4);
  int*    boff     = (int*)alloc((size_t)NB * 4);
  int2*   csr_pack = (int2*)alloc((size_t)E * 8);
  __bf16* xb  = (__bf16*)alloc((size_t)N * D * 2);
  __bf16* hb  = (__bf16*)alloc((size_t)N * H * 2);
  unsigned char* cb = (unsigned char*)alloc((size_t)N * H);   // fp8 pre-activations
  __bf16* w1t = (__bf16*)alloc((size_t)D * H * 2);
  __bf16* w2t = (__bf16*)alloc((size_t)H * H * 2);
  __bf16* wct = (__bf16*)alloc((size_t)2 * Z * H * 2);

  hipMemsetAsync(cnt, 0, (size_t)N * 4, stream);
  hipMemsetAsync(cur, 0, (size_t)N * 4, stream);

  count_kernel<<<1250, 256, 0, stream>>>(dst, cnt, E);
  scan1_kernel<<<NB, 1024, 0, stream>>>(cnt, rowptr, dinv, bsum, N);
  scan2_kernel<<<1, 64, 0, stream>>>(bsum, boff, rowptr, NB, N);
  scan3_kernel<<<NB, 1024, 0, stream>>>(rowptr, boff, N);
  fill_kernel<<<1250, 256, 0, stream>>>(src, dst, rowptr, cur, dinv, csr_pack, E);
  convert_kernel<<<12800, 256, 0, stream>>>(x, W1, W2, Wmu, Wlv, xb, w1t, w2t, wct);

  // layer 1
  gemm_bt<<<((N + 127) / 128) * (H / 128), 256, 0, stream>>>(xb, w1t, cb, N, H, D, H / 128);
  prop_kernel<8, 0><<<2500, 512, 0, stream>>>(cb, rowptr, csr_pack, dinv,
                                              b1, nullptr, nullptr, nullptr, hb, nullptr, N);
  // layer 2
  gemm_bt<<<((N + 127) / 128) * (H / 128), 256, 0, stream>>>(hb, w2t, cb, N, H, H, H / 128);
  prop_kernel<8, 1><<<2500, 512, 0, stream>>>(cb, rowptr, csr_pack, dinv,
                                              b2, nullptr, nullptr, nullptr, xb, nullptr, N);
  // heads (mu || lv) + reparameterize
  gemm_bt<<<((N + 127) / 128) * ((2 * Z) / 128), 256, 0, stream>>>(xb, wct, cb, N, 2 * Z, H, (2 * Z) / 128);
  prop_kernel<4, 2><<<2500, 512, 0, stream>>>(cb, rowptr, csr_pack, dinv,
                                              nullptr, bmu, blv, eps, nullptr, out, N);
}

// Round 7
// 182.189 us; speedup vs baseline: 1.2961x; 1.1088x over previous
//
#include <hip/hip_runtime.h>

typedef __bf16 bf16x8 __attribute__((ext_vector_type(8)));
typedef __bf16 bf16x4 __attribute__((ext_vector_type(4)));
typedef float  f32x4  __attribute__((ext_vector_type(4)));
typedef float  f32x2  __attribute__((ext_vector_type(2)));

#define GLDS16(g, l) __builtin_amdgcn_global_load_lds( \
    (const __attribute__((address_space(1))) void*)(g), \
    (__attribute__((address_space(3))) void*)(l), 16, 0, 0)

// fp8 e4m3 (OCP on gfx950). cb holds 64*y in fp8; 1/64 folded into coefs.
#define FP8_SCALE 64.0f
#define FP8_INV   (1.0f / 64.0f)

__device__ __forceinline__ unsigned char fp8_of_f32(float v) {
  return (unsigned char)(__builtin_amdgcn_cvt_pk_fp8_f32(v, v, 0, false) & 0xff);
}
__device__ __forceinline__ void dec4(unsigned int u, float* o) {
  f32x2 lo = __builtin_amdgcn_cvt_pk_f32_fp8(u, false);
  f32x2 hi = __builtin_amdgcn_cvt_pk_f32_fp8(u, true);
  o[0] = lo[0]; o[1] = lo[1]; o[2] = hi[0]; o[3] = hi[1];
}

// ---------------- fused prep: count + x->bf16 + LDS-tiled weight transposes ----------------
// blocks [0,640): degree count; [640,1280): weight transpose tiles; [1280,11280): x convert.

#define CNT_BLKS 640
#define WT_BLKS  640

__global__ __launch_bounds__(256) void prep_kernel(
    const int* __restrict__ dstv, int* __restrict__ cnt, int E,
    const float* __restrict__ x, __bf16* __restrict__ xb,
    const float* __restrict__ W1, const float* __restrict__ W2,
    const float* __restrict__ Wmu, const float* __restrict__ Wlv,
    __bf16* __restrict__ w1t, __bf16* __restrict__ w2t, __bf16* __restrict__ wct) {
  const int b = blockIdx.x;
  if (b < CNT_BLKS) {
    int idx = b * 256 + threadIdx.x;
    for (int e = idx; e < E; e += CNT_BLKS * 256) atomicAdd(&cnt[dstv[e]], 1);
  } else if (b < CNT_BLKS + WT_BLKS) {
    __shared__ float tile[32][33];
    int t = b - CNT_BLKS;
    const float* S; __bf16* D; int kt, ntl, drow, snw;
    if (t < 256)      { S = W1;  D = w1t; kt = t & 15;        ntl = t >> 4;        drow = ntl * 32;       snw = 512; }
    else if (t < 512) { int u = t - 256; S = W2;  D = w2t; kt = u & 15; ntl = u >> 4; drow = ntl * 32;       snw = 512; }
    else if (t < 576) { int u = t - 512; S = Wmu; D = wct; kt = u & 15; ntl = u >> 4; drow = ntl * 32;       snw = 128; }
    else              { int u = t - 576; S = Wlv; D = wct; kt = u & 15; ntl = u >> 4; drow = 128 + ntl * 32; snw = 128; }
    const int k0 = kt * 32, n0 = ntl * 32;
    const int r = threadIdx.x >> 5, c = threadIdx.x & 31;
    #pragma unroll
    for (int p = 0; p < 4; p++)
      tile[r + p * 8][c] = S[(k0 + r + p * 8) * snw + n0 + c];
    __syncthreads();
    #pragma unroll
    for (int p = 0; p < 4; p++)
      D[(drow + r + p * 8) * 512 + k0 + c] = (__bf16)tile[c][r + p * 8];
  } else {
    int id = (b - CNT_BLKS - WT_BLKS) * 256 + threadIdx.x;   // [0, 2,560,000)
    if (id < 2560000) {
      float4 v = ((const float4*)x)[id];
      bf16x4 o; o[0] = (__bf16)v.x; o[1] = (__bf16)v.y; o[2] = (__bf16)v.z; o[3] = (__bf16)v.w;
      ((bf16x4*)xb)[id] = o;
    }
  }
}

// ---------------- graph prep: scan ----------------

// phase 1: per-1024-block exclusive scan (wave shuffle + LDS wave-combine), dinv fused
__global__ __launch_bounds__(1024) void scan1_kernel(const int* __restrict__ cnt,
                                                     int* __restrict__ rowptr,
                                                     float* __restrict__ dinv,
                                                     int* __restrict__ bsum, int n) {
  __shared__ int wsum[16];
  const int t = threadIdx.x, b = blockIdx.x;
  const int gid = b * 1024 + t;
  const int lane = t & 63, w = t >> 6;
  int val = (gid < n) ? cnt[gid] : 0;
  if (gid < n) dinv[gid] = rsqrtf((float)val + 1.0f);
  int incl = val;
  #pragma unroll
  for (int off = 1; off < 64; off <<= 1) {
    int u = __shfl_up(incl, off);
    if (lane >= off) incl += u;
  }
  if (lane == 63) wsum[w] = incl;
  __syncthreads();
  if (w == 0) {
    int v = (lane < 16) ? wsum[lane] : 0;
    int iv = v;
    #pragma unroll
    for (int off = 1; off < 16; off <<= 1) {
      int u = __shfl_up(iv, off);
      if (lane >= off) iv += u;
    }
    if (lane < 16) wsum[lane] = iv - v;
    if (lane == 15) bsum[b] = iv;
  }
  __syncthreads();
  if (gid < n) rowptr[gid] = wsum[w] + incl - val;
}

// phase 2+3 fused: each block adds its prefix of bsum; last block writes rowptr[n]
__global__ __launch_bounds__(1024) void scan23_kernel(int* __restrict__ rowptr,
                                                      const int* __restrict__ bsum,
                                                      int n, int nb) {
  __shared__ int off_s;
  const int b = blockIdx.x;
  if (threadIdx.x == 0) {
    int run = 0;
    for (int i = 0; i < b; i++) run += bsum[i];
    off_s = run;
    if (b == nb - 1) rowptr[n] = run + bsum[b];
  }
  __syncthreads();
  int gid = b * 1024 + threadIdx.x;
  if (gid < n) rowptr[gid] += off_s;
}

// ---------------- GEMM tile (device fn): C[M,N] = A[M,K] @ Bt[N,K]^T, fp8 out ----------------
// 128x128 tile, BK=32, double-buffered LDS, counted vmcnt(4), XOR granule swizzle
// both-sides, bijective XCD chunking over the ngb gemm blocks.

__device__ __forceinline__ void gemm_tile(int orig, int nb,
                                          const __bf16* __restrict__ A,
                                          const __bf16* __restrict__ Bt,
                                          unsigned char* __restrict__ C,
                                          int M, int N, int K, int ntiles_n) {
  __shared__ __align__(16) __bf16 sA[2][128 * 32];
  __shared__ __align__(16) __bf16 sB[2][128 * 32];
  const int q = nb >> 3, r = nb & 7;
  const int xcd = orig & 7, sub = orig >> 3;
  const int pos = (xcd < r) ? (xcd * (q + 1) + sub) : (r * (q + 1) + (xcd - r) * q + sub);
  const int m0 = (pos / ntiles_n) * 128, n0 = (pos % ntiles_n) * 128;

  const int tid = threadIdx.x;
  const int wave = tid >> 6, lane = tid & 63;
  const int wr = wave >> 1, wc = wave & 1;
  f32x4 acc[4][4] = {};
  const int srow = lane >> 2;
  const int sg   = (lane & 3) ^ ((srow >> 1) & 3);
  const int nt = K >> 5;

  auto STAGE = [&](int bb, int k0) {
    #pragma unroll
    for (int c = 0; c < 2; ++c) {
      int chunk = wave * 2 + c;
      int row = chunk * 16 + srow;
      int ga = m0 + row; if (ga >= M) ga = M - 1;
      GLDS16(A  + (long)ga * K         + k0 + sg * 8, sA[bb] + chunk * 512);
      GLDS16(Bt + (long)(n0 + row) * K + k0 + sg * 8, sB[bb] + chunk * 512);
    }
  };

  STAGE(0, 0);
  for (int t = 0; t < nt; ++t) {
    const int cur = t & 1;
    if (t + 1 < nt) {
      STAGE(cur ^ 1, (t + 1) << 5);
      asm volatile("s_waitcnt vmcnt(4)" ::: "memory");
    } else {
      asm volatile("s_waitcnt vmcnt(0)" ::: "memory");
    }
    __builtin_amdgcn_s_barrier();
    __builtin_amdgcn_sched_barrier(0);

    const int fr = lane & 15, gbase = lane >> 4;
    const int gs = gbase ^ ((fr >> 1) & 3);
    bf16x8 af[4], bfr[4];
    #pragma unroll
    for (int mi = 0; mi < 4; mi++)
      af[mi] = *(const bf16x8*)(sA[cur] + (wr * 64 + mi * 16 + fr) * 32 + gs * 8);
    #pragma unroll
    for (int ni = 0; ni < 4; ni++)
      bfr[ni] = *(const bf16x8*)(sB[cur] + (wc * 64 + ni * 16 + fr) * 32 + gs * 8);
    #pragma unroll
    for (int mi = 0; mi < 4; mi++)
      #pragma unroll
      for (int ni = 0; ni < 4; ni++)
        acc[mi][ni] = __builtin_amdgcn_mfma_f32_16x16x32_bf16(af[mi], bfr[ni], acc[mi][ni], 0, 0, 0);
    asm volatile("s_waitcnt lgkmcnt(0)" ::: "memory");
    __builtin_amdgcn_sched_barrier(0);
    __builtin_amdgcn_s_barrier();
  }

  const int crow0 = (lane >> 4) * 4, ccol = lane & 15;
  #pragma unroll
  for (int mi = 0; mi < 4; mi++)
    #pragma unroll
    for (int ni = 0; ni < 4; ni++)
      #pragma unroll
      for (int r2 = 0; r2 < 4; r2++) {
        int row = m0 + wr * 64 + mi * 16 + crow0 + r2;
        if (row < M)
          C[(long)row * N + n0 + wc * 64 + ni * 16 + ccol] =
              fp8_of_f32(acc[mi][ni][r2] * FP8_SCALE);
      }
}

__global__ __launch_bounds__(256, 4) void gemm_bt(const __bf16* __restrict__ A,
                                                  const __bf16* __restrict__ Bt,
                                                  unsigned char* __restrict__ C,
                                                  int M, int N, int K, int ntiles_n, int ngb) {
  gemm_tile(blockIdx.x, ngb, A, Bt, C, M, N, K, ntiles_n);
}

// fused: blocks [0,ngb) run layer-1 GEMM; remaining blocks build the packed CSR
__global__ __launch_bounds__(256, 4) void gemm1_fill_kernel(
    const __bf16* __restrict__ A, const __bf16* __restrict__ Bt,
    unsigned char* __restrict__ C, int M, int N, int K, int ntiles_n, int ngb,
    const int* __restrict__ src, const int* __restrict__ dstv,
    const int* __restrict__ rowptr, int* __restrict__ cur,
    const float* __restrict__ dinv, int2* __restrict__ csr_pack, int E) {
  if (blockIdx.x < (unsigned)ngb) {
    gemm_tile(blockIdx.x, ngb, A, Bt, C, M, N, K, ntiles_n);
  } else {
    int idx = (blockIdx.x - ngb) * 256 + threadIdx.x;
    int stride = (gridDim.x - ngb) * 256;
    for (int e = idx; e < E; e += stride) {
      int s = src[e], d = dstv[e];
      int slot = rowptr[d] + atomicAdd(&cur[d], 1);
      int2 p; p.x = s; p.y = __float_as_int(dinv[s] * dinv[d] * FP8_INV);
      csr_pack[slot] = p;
    }
  }
}

// ---------------- propagation: out = agg + self*h + b, fused epilogues ----------------

template<int EPL> struct LSel;
template<> struct LSel<8> { typedef uint2 T; };
template<> struct LSel<4> { typedef unsigned int T; };

template<int EPL, int MODE>
__global__ __launch_bounds__(512) void prop_kernel(
    const unsigned char* __restrict__ Cin, const int* __restrict__ rowptr,
    const int2* __restrict__ csr_pack,
    const float* __restrict__ dinv, const float* __restrict__ bias,
    const float* __restrict__ bmu, const float* __restrict__ blv,
    const float* __restrict__ eps,
    __bf16* __restrict__ hout, float* __restrict__ zout, int n) {
  constexpr int F = EPL * 64;                    // bytes per row
  typedef typename LSel<EPL>::T VecT;
  const int lane = threadIdx.x & 63;
  const int i = blockIdx.x * (blockDim.x >> 6) + (threadIdx.x >> 6);
  if (i >= n) return;
  const unsigned char* __restrict__ Clane = Cin + lane * EPL;

  auto decAll = [&](VecT v, float* o) {
    if constexpr (EPL == 8) { dec4(v.x, o); dec4(v.y, o + 4); }
    else                    { dec4(v, o); }
  };

  float acc[EPL];
  {
    const float di = dinv[i];
    const float sc = di * di * FP8_INV;
    VecT v = *(const VecT*)(Clane + (size_t)i * F);
    float dv[EPL];
    decAll(v, dv);
    #pragma unroll
    for (int j = 0; j < EPL; j++) acc[j] = sc * dv[j];
  }
  int e = rowptr[i];
  const int e1 = rowptr[i + 1];
  for (; e + 8 <= e1; e += 8) {
    int2 p[8];
    #pragma unroll
    for (int q = 0; q < 8; q++) p[q] = csr_pack[e + q];
    VecT v[8];
    #pragma unroll
    for (int q = 0; q < 8; q++) v[q] = *(const VecT*)(Clane + (size_t)p[q].x * F);
    #pragma unroll
    for (int q = 0; q < 8; q++) {
      float c = __int_as_float(p[q].y);
      float dv[EPL];
      decAll(v[q], dv);
      #pragma unroll
      for (int j = 0; j < EPL; j++) acc[j] += c * dv[j];
    }
  }
  for (; e + 4 <= e1; e += 4) {
    int2 p[4];
    #pragma unroll
    for (int q = 0; q < 4; q++) p[q] = csr_pack[e + q];
    VecT v[4];
    #pragma unroll
    for (int q = 0; q < 4; q++) v[q] = *(const VecT*)(Clane + (size_t)p[q].x * F);
    #pragma unroll
    for (int q = 0; q < 4; q++) {
      float c = __int_as_float(p[q].y);
      float dv[EPL];
      decAll(v[q], dv);
      #pragma unroll
      for (int j = 0; j < EPL; j++) acc[j] += c * dv[j];
    }
  }
  for (; e < e1; ++e) {
    int2 p = csr_pack[e];
    float c = __int_as_float(p.y);
    VecT v = *(const VecT*)(Clane + (size_t)p.x * F);
    float dv[EPL];
    decAll(v, dv);
    #pragma unroll
    for (int j = 0; j < EPL; j++) acc[j] += c * dv[j];
  }

  if constexpr (MODE == 0 || MODE == 1) {
    float ss = 0.f;
    #pragma unroll
    for (int j = 0; j < EPL; j++) {
      acc[j] += bias[lane * EPL + j];
      acc[j] = fmaxf(acc[j], 0.f);
      ss += acc[j] * acc[j];
    }
    float scale = 1.f;
    if constexpr (MODE == 0) {
      #pragma unroll
      for (int off = 32; off > 0; off >>= 1) ss += __shfl_xor(ss, off);
      scale = 1.f / fmaxf(sqrtf(ss), 1e-12f);
    }
    bf16x8 o;
    #pragma unroll
    for (int j = 0; j < EPL; j++) o[j] = (__bf16)(acc[j] * scale);
    *(bf16x8*)(hout + (size_t)i * 512 + lane * EPL) = o;
  } else {
    const bool ismu = lane < 32;
    const int cb4 = (ismu ? lane : lane - 32) * 4;
    float v[4];
    #pragma unroll
    for (int j = 0; j < 4; j++) v[j] = acc[j] + (ismu ? bmu[cb4 + j] : blv[cb4 + j]);
    const size_t NZ = (size_t)n * 128;
    float* dstp = ismu ? (zout + NZ + (size_t)i * 128 + cb4)
                       : (zout + 2 * NZ + (size_t)i * 128 + cb4);
    float4 st; st.x = v[0]; st.y = v[1]; st.z = v[2]; st.w = v[3];
    *(float4*)dstp = st;
    float ov[4];
    #pragma unroll
    for (int j = 0; j < 4; j++) ov[j] = __shfl_xor(v[j], 32);
    if (ismu) {
      float4 ev = *(const float4*)(eps + (size_t)i * 128 + cb4);
      float4 zs;
      zs.x = v[0] + ev.x * expf(0.5f * ov[0]);
      zs.y = v[1] + ev.y * expf(0.5f * ov[1]);
      zs.z = v[2] + ev.z * expf(0.5f * ov[2]);
      zs.w = v[3] + ev.w * expf(0.5f * ov[3]);
      *(float4*)(zout + (size_t)i * 128 + cb4) = zs;
    }
  }
}

// ---------------- launch ----------------

extern "C" void kernel_launch(void* const* d_in, const int* in_sizes, int n_in,
                              void* d_out, int out_size, void* d_ws, size_t ws_size,
                              hipStream_t stream) {
  const float* x   = (const float*)d_in[0];
  const int*   ei  = (const int*)d_in[1];
  const float* eps = (const float*)d_in[2];
  const float* W1  = (const float*)d_in[3];
  const float* b1  = (const float*)d_in[4];
  const float* W2  = (const float*)d_in[5];
  const float* b2  = (const float*)d_in[6];
  const float* Wmu = (const float*)d_in[7];
  const float* bmu = (const float*)d_in[8];
  const float* Wlv = (const float*)d_in[9];
  const float* blv = (const float*)d_in[10];
  float* out = (float*)d_out;

  const int N = 20000, E = 320000, D = 512, H = 512, Z = 128;
  const int* src = ei;
  const int* dst = ei + E;
  const int NB = (N + 1023) / 1024;     // 20 scan blocks

  char* p = (char*)d_ws;
  auto alloc = [&](size_t bytes) { char* r = p; p += (bytes + 255) & ~(size_t)255; return r; };
  int*    cnt      = (int*)alloc((size_t)N * 4);       // adjacent:
  int*    cur      = (int*)alloc((size_t)N * 4);       //   one memset covers both
  int*    rowptr   = (int*)alloc((size_t)(N + 1) * 4);
  float*  dinv     = (float*)alloc((size_t)N * 4);
  int*    bsum     = (int*)alloc((size_t)NB * 4);
  int2*   csr_pack = (int2*)alloc((size_t)E * 8);
  __bf16* xb  = (__bf16*)alloc((size_t)N * D * 2);
  __bf16* hb  = (__bf16*)alloc((size_t)N * H * 2);
  unsigned char* cb = (unsigned char*)alloc((size_t)N * H);   // fp8 pre-activations
  __bf16* w1t = (__bf16*)alloc((size_t)D * H * 2);
  __bf16* w2t = (__bf16*)alloc((size_t)H * H * 2);
  __bf16* wct = (__bf16*)alloc((size_t)2 * Z * H * 2);

  hipMemsetAsync(cnt, 0, ((size_t)N * 4 + 255 & ~(size_t)255) + (size_t)N * 4, stream);

  prep_kernel<<<CNT_BLKS + WT_BLKS + 10000, 256, 0, stream>>>(
      dst, cnt, E, x, xb, W1, W2, Wmu, Wlv, w1t, w2t, wct);
  scan1_kernel<<<NB, 1024, 0, stream>>>(cnt, rowptr, dinv, bsum, N);
  scan23_kernel<<<NB, 1024, 0, stream>>>(rowptr, bsum, N, NB);

  const int NGB1 = ((N + 127) / 128) * (H / 128);     // 628
  gemm1_fill_kernel<<<NGB1 + 1250, 256, 0, stream>>>(
      xb, w1t, cb, N, H, D, H / 128, NGB1,
      src, dst, rowptr, cur, dinv, csr_pack, E);
  prop_kernel<8, 0><<<2500, 512, 0, stream>>>(cb, rowptr, csr_pack, dinv,
                                              b1, nullptr, nullptr, nullptr, hb, nullptr, N);
  // layer 2
  gemm_bt<<<NGB1, 256, 0, stream>>>(hb, w2t, cb, N, H, H, H / 128, NGB1);
  prop_kernel<8, 1><<<2500, 512, 0, stream>>>(cb, rowptr, csr_pack, dinv,
                                              b2, nullptr, nullptr, nullptr, xb, nullptr, N);
  // heads (mu || lv) + reparameterize
  const int NGB3 = ((N + 127) / 128) * ((2 * Z) / 128);   // 314
  gemm_bt<<<NGB3, 256, 0, stream>>>(xb, wct, cb, N, 2 * Z, H, (2 * Z) / 128, NGB3);
  prop_kernel<4, 2><<<2500, 512, 0, stream>>>(cb, rowptr, csr_pack, dinv,
                                              nullptr, bmu, blv, eps, nullptr, out, N);
}